// Round 12
// baseline (205.613 us; speedup 1.0000x reference)
//
#include <hip/hip_runtime.h>
#include <math.h>

#define LSEQ 4096   // D*H*W = 16*16*16
#define CIN  128
#define DI   64     // d_inner
#define NS   16     // d_state
#define NP   4      // parts
#define NJ   4      // jobs = (b, mixer) pairs
#define NSEQ 16     // NJ * NP independent mamba sequences
#define NC   128    // scan chunks
#define LC   32     // chunk length (NC*LC = LSEQ)
#define LOG2E 1.44269504f
#define LN2   0.6931471806f

__device__ __forceinline__ int mixer_of(const int* did, int j){
  if((j&1)==0) return 0;
  int d = did[j>>1];
  return 1 + (d < 1 ? d : 1);
}
// native transcendentals: v_exp_f32 / v_log_f32 / v_rcp_f32
__device__ __forceinline__ float fexp2(float x){ return __builtin_amdgcn_exp2f(x); }
__device__ __forceinline__ float silu_f(float x){
  return x*__builtin_amdgcn_rcpf(1.f + fexp2(-x*LOG2E));
}
__device__ __forceinline__ float softplus_f(float x){
  return x>20.f ? x : LN2*__builtin_amdgcn_logf(1.f + fexp2(x*LOG2E));
}

// ---------------- K1: LN1 + in_proj. 16 l per block, in-place LN, single LDS buffer ----------------
__global__ __launch_bounds__(256) void k1_ln_inproj(
  const float* __restrict__ x, const int* __restrict__ did,
  const float* __restrict__ ln_g, const float* __restrict__ ln_b,
  const float* __restrict__ in_w,
  float* __restrict__ xnb, float* __restrict__ xzr, float* __restrict__ zb)
{
  const int j = blockIdx.y, b = j>>1, t = threadIdx.x;
  const int l0 = blockIdx.x*16;
  const int m = mixer_of(did, j);
  __shared__ float s_xn[16][132];   // raw x, then normalized in place
  __shared__ float s_mu[16], s_rs[16];

  #pragma unroll
  for(int rep=0; rep<2; rep++){
    int fidx = t + rep*256;          // [0,512)
    int c = fidx>>2, fq = fidx&3;    // 128 c x 4 float4 (16 l)
    float4 v = *(const float4*)(x + ((size_t)b*CIN+c)*LSEQ + l0 + fq*4);
    s_xn[fq*4+0][c]=v.x; s_xn[fq*4+1][c]=v.y; s_xn[fq*4+2][c]=v.z; s_xn[fq*4+3][c]=v.w;
  }
  float wreg[32];
  {
    const float4* wp = (const float4*)(in_w + (size_t)m*4096 + (size_t)(t&127)*32);
    #pragma unroll
    for(int i=0;i<8;i++){
      float4 v = wp[i];
      wreg[i*4+0]=v.x; wreg[i*4+1]=v.y; wreg[i*4+2]=v.z; wreg[i*4+3]=v.w;
    }
  }
  __syncthreads();

  {
    const int wv = t>>6, lane = t&63;
    if(wv < 2){
      const int lw = lane&7, g = lane>>3;
      const int ll = wv*8 + lw;
      const float4* xr4 = (const float4*)(&s_xn[ll][g*16]);
      float sum=0.f, vs=0.f;
      #pragma unroll
      for(int k=0;k<4;k++){
        float4 v = xr4[k];
        sum += (v.x+v.y)+(v.z+v.w);
        vs  += v.x*v.x + v.y*v.y + v.z*v.z + v.w*v.w;
      }
      sum += __shfl_xor(sum,8);  vs += __shfl_xor(vs,8);
      sum += __shfl_xor(sum,16); vs += __shfl_xor(vs,16);
      sum += __shfl_xor(sum,32); vs += __shfl_xor(vs,32);
      float mu  = sum*(1.f/128.f);
      float var = fmaxf(vs*(1.f/128.f) - mu*mu, 0.f);
      if(g==0){ s_mu[ll]=mu; s_rs[ll]=rsqrtf(var+1e-5f); }
    }
  }
  __syncthreads();

  #pragma unroll
  for(int rep=0; rep<8; rep++){
    int idx = t + rep*256;           // [0,2048)
    int ll = idx>>7, c = idx&127;
    float xn = (s_xn[ll][c]-s_mu[ll])*s_rs[ll]*ln_g[m*128+c] + ln_b[m*128+c];
    s_xn[ll][c] = xn;
    xnb[((size_t)j*LSEQ + l0+ll)*128 + c] = xn;
  }
  __syncthreads();

  const int e = t&127, hh = t>>7;
  for(int ll=hh*8; ll<hh*8+8; ++ll){
    #pragma unroll
    for(int q=0;q<4;q++){
      const float4* xr4 = (const float4*)(&s_xn[ll][q*32]);
      float acc=0.f;
      #pragma unroll
      for(int k4=0;k4<8;k4++){
        float4 xv = xr4[k4];
        acc += xv.x*wreg[k4*4+0] + xv.y*wreg[k4*4+1]
             + xv.z*wreg[k4*4+2] + xv.w*wreg[k4*4+3];
      }
      size_t base = ((size_t)(j*NP+q)*LSEQ + l0+ll)*64;
      if(e<64) xzr[base+e]=acc; else zb[base+e-64]=acc;
    }
  }
}

// ---- K2: conv + SiLU + x_proj(all-lane) + dt/softplus + fused chunk summary (P,E) ----
__global__ __launch_bounds__(256) void k2_conv_xproj_pe(
  const int* __restrict__ did,
  const float* __restrict__ conv_w, const float* __restrict__ conv_b,
  const float* __restrict__ xp_w, const float* __restrict__ dt_w, const float* __restrict__ dt_b,
  const float* __restrict__ A_log,
  const float* __restrict__ xzr, float* __restrict__ dxb,
  float* __restrict__ bmb, float* __restrict__ cmb,
  float* __restrict__ pb, float* __restrict__ eb)
{
  const int seq = blockIdx.y, j = seq>>2, t = threadIdx.x;
  const int chunk = blockIdx.x;
  const int l0 = chunk*32;
  const int m = mixer_of(did, j);
  const int d = t&63, r = t>>6;
  __shared__ float  s_xi[32][64];
  __shared__ float  s_dl[32][64];
  __shared__ float  s_bS[32][16];
  __shared__ float  s_dbc[32][2];
  __shared__ float  s_cwT[4][64];
  __shared__ float  s_xpw01[2][64];
  __shared__ float  s_cb[64], s_dtw[128], s_dtb[64];

  float lz[11];
  #pragma unroll
  for(int i=0;i<11;i++){
    int l = l0 + r*8 - 3 + i;
    lz[i] = (l>=0) ? xzr[((size_t)seq*LSEQ + l)*64 + d] : 0.f;
  }
  { int k=t>>6, dd=t&63; s_cwT[k][dd]=conv_w[m*256+dd*4+k]; }
  if(t<64){ s_cb[t]=conv_b[m*64+t]; s_dtb[t]=dt_b[m*64+t]; }
  if(t<128){ s_dtw[t]=dt_w[m*128+t]; s_xpw01[t>>6][t&63]=xp_w[m*2176 + t]; }
  const int o2 = t&31, rg = t>>5;
  float wreg[64];
  {
    const float4* wp = (const float4*)(xp_w + (size_t)m*2176 + (size_t)(2+o2)*64);
    #pragma unroll
    for(int k4=0;k4<16;k4++){
      float4 v = wp[k4];
      wreg[k4*4+0]=v.x; wreg[k4*4+1]=v.y; wreg[k4*4+2]=v.z; wreg[k4*4+3]=v.w;
    }
  }
  __syncthreads();

  float xir[8];
  {
    float cw0=s_cwT[0][d], cw1=s_cwT[1][d], cw2=s_cwT[2][d], cw3=s_cwT[3][d], cb=s_cb[d];
    #pragma unroll
    for(int i=0;i<8;i++){
      float xc = cb + lz[i]*cw0 + lz[i+1]*cw1 + lz[i+2]*cw2 + lz[i+3]*cw3;
      xir[i] = silu_f(xc);
      s_xi[r*8+i][d] = xir[i];
    }
  }

  {
    float pr[8];
    #pragma unroll
    for(int i=0;i<8;i++){
      float p0 = xir[i]*s_xpw01[0][d];
      float p1 = xir[i]*s_xpw01[1][d];
      float q0 = p0 + __shfl_xor(p0,1);
      float q1 = p1 + __shfl_xor(p1,1);
      pr[i] = (d&1) ? q1 : q0;
    }
    #pragma unroll
    for(int off=2; off<64; off<<=1){
      #pragma unroll
      for(int i=0;i<8;i++) pr[i] += __shfl_xor(pr[i], off);
    }
    if(d<2){
      #pragma unroll
      for(int i=0;i<8;i++) s_dbc[r*8+i][d] = pr[i];
    }
  }
  __syncthreads();

  {
    float w0=s_dtw[d*2], w1=s_dtw[d*2+1], bb=s_dtb[d];
    #pragma unroll
    for(int i=0;i<8;i++){
      int ll=r*8+i;
      float dtv = s_dbc[ll][0]*w0 + s_dbc[ll][1]*w1 + bb;
      float dlv = softplus_f(dtv);
      s_dl[ll][d] = dlv;
      *(float2*)(dxb + ((size_t)seq*LSEQ + l0+ll)*128 + d*2) = make_float2(dlv, xir[i]);
    }
  }

  {
    #pragma unroll
    for(int ip=0; ip<2; ip++){
      int ll = rg*4 + ip*2;
      const float4* xa=(const float4*)&s_xi[ll][0];
      const float4* xb=(const float4*)&s_xi[ll+1][0];
      float a0=0.f,a1=0.f,b0=0.f,b1=0.f;
      #pragma unroll
      for(int k=0;k<16;k+=2){
        float4 u=xa[k], u2=xa[k+1], v=xb[k], v2=xb[k+1];
        a0 += u.x *wreg[4*k+0]+u.y *wreg[4*k+1]+u.z *wreg[4*k+2]+u.w *wreg[4*k+3];
        a1 += u2.x*wreg[4*k+4]+u2.y*wreg[4*k+5]+u2.z*wreg[4*k+6]+u2.w*wreg[4*k+7];
        b0 += v.x *wreg[4*k+0]+v.y *wreg[4*k+1]+v.z *wreg[4*k+2]+v.w *wreg[4*k+3];
        b1 += v2.x*wreg[4*k+4]+v2.y*wreg[4*k+5]+v2.z*wreg[4*k+6]+v2.w*wreg[4*k+7];
      }
      float A=a0+a1, Bv=b0+b1;
      if(o2<16){
        s_bS[ll][o2]=A; s_bS[ll+1][o2]=Bv;
        bmb[((size_t)seq*LSEQ + l0+ll  )*16 + o2]=A;
        bmb[((size_t)seq*LSEQ + l0+ll+1)*16 + o2]=Bv;
      } else {
        cmb[((size_t)seq*LSEQ + l0+ll  )*16 + o2-16]=A;
        cmb[((size_t)seq*LSEQ + l0+ll+1)*16 + o2-16]=Bv;
      }
    }
  }
  __syncthreads();

  // ---- fused chunk summary: thread = (d, s-quad sq=r), 4 states each ----
  {
    const int sq = r;              // wave-uniform
    float as_q[4], as0;
    {
      const float* ap = A_log + (size_t)m*1024 + d*16;
      as0 = -expf(ap[0])*LOG2E;
      #pragma unroll
      for(int k=0;k<4;k++) as_q[k] = -expf(ap[sq*4+k])*LOG2E;
    }
    bool stl = true;
    #pragma unroll
    for(int k=0;k<4;k++){ float ex=(float)(sq*4+k+1)*as0; stl = stl && (fabsf(as_q[k]-ex) <= 1e-4f*fabsf(ex)); }
    const bool structured = (__ballot(stl) == ~0ull);

    float E[4] = {0.f,0.f,0.f,0.f};
    float Sdl = 0.f;

    // FAST: p_k = q^(4sq+1+k), q = exp2(dl*as0). ONE exp2 per step.
    #define PSTEPF(i_, P0CODE) { \
      float dl = s_dl[i_][d]; \
      float u  = dl * s_xi[i_][d]; \
      Sdl += dl; \
      const float4 bv = *(const float4*)(&s_bS[i_][sq*4]); \
      float q = fexp2(dl*as0); \
      float q2 = q*q; float q4 = q2*q2; (void)q2; (void)q4; \
      float p0 = (P0CODE); \
      float p1 = p0*q, p2 = p1*q, p3 = p2*q; \
      E[0]=fmaf(p0,E[0],u*bv.x); E[1]=fmaf(p1,E[1],u*bv.y); \
      E[2]=fmaf(p2,E[2],u*bv.z); E[3]=fmaf(p3,E[3],u*bv.w); }

    #define PSTEPG(i_) { \
      float dl = s_dl[i_][d]; \
      float u  = dl * s_xi[i_][d]; \
      Sdl += dl; \
      const float4 bv = *(const float4*)(&s_bS[i_][sq*4]); \
      float p_[4]; \
      _Pragma("unroll") for(int k=0;k<4;k++) p_[k]=fexp2(dl*as_q[k]); \
      E[0]=fmaf(p_[0],E[0],u*bv.x); E[1]=fmaf(p_[1],E[1],u*bv.y); \
      E[2]=fmaf(p_[2],E[2],u*bv.z); E[3]=fmaf(p_[3],E[3],u*bv.w); }

    if(structured){
      if(sq==0){
        #pragma unroll 4
        for(int i=0;i<LC;i++){ PSTEPF(i, q) }
      } else if(sq==1){
        #pragma unroll 4
        for(int i=0;i<LC;i++){ PSTEPF(i, q4*q) }
      } else if(sq==2){
        #pragma unroll 4
        for(int i=0;i<LC;i++){ PSTEPF(i, (q4*q4)*q) }
      } else {
        #pragma unroll 4
        for(int i=0;i<LC;i++){ PSTEPF(i, ((q4*q4)*q4)*q) }
      }
    } else {
      #pragma unroll 4
      for(int i=0;i<LC;i++){ PSTEPG(i) }
    }
    #undef PSTEPF
    #undef PSTEPG

    size_t oo=(((size_t)seq*NC+chunk)*64+d)*16 + sq*4;
    *(float4*)(pb+oo) = make_float4(fexp2(Sdl*as_q[0]),fexp2(Sdl*as_q[1]),
                                    fexp2(Sdl*as_q[2]),fexp2(Sdl*as_q[3]));
    *(float4*)(eb+oo) = make_float4(E[0],E[1],E[2],E[3]);
  }
}

// -------- K3C4: self-combine h0 + rescan + gate + out_proj + skip. 2 chunks x 2 s-half waves --------
__global__ __launch_bounds__(256) void k3c4_scan_outproj(
  const int* __restrict__ did, const float* __restrict__ A_log, const float* __restrict__ Dp,
  const float* __restrict__ dxb,
  const float* __restrict__ bmb, const float* __restrict__ cmb,
  const float* __restrict__ zb,
  const float* __restrict__ pb, const float* __restrict__ eb,
  const float* __restrict__ out_w, const float* __restrict__ skipv,
  const float* __restrict__ xnb, float* __restrict__ xmb)
{
  const int seq=blockIdx.y, j=seq>>2, p=seq&3, t=threadIdx.x;
  const int wave=t>>6, d=t&63;
  const int cl=wave>>1, sh=wave&1, sh8=sh*8;
  const int chunk=blockIdx.x*2+cl;
  const int l0=blockIdx.x*2*LC;            // 64 l per block
  const int m=mixer_of(did,j);
  __shared__ float s_b[2*LC*NS];           // 4KB
  __shared__ float s_c[2*LC*NS];           // 4KB
  __shared__ float s_y0[64*64];            // 16KB
  __shared__ float s_y1[64*64];            // 16KB
  {
    const float4* bsrc=(const float4*)(bmb + ((size_t)seq*LSEQ + l0)*NS);
    const float4* csrc=(const float4*)(cmb + ((size_t)seq*LSEQ + l0)*NS);
    ((float4*)s_b)[t]=bsrc[t];
    ((float4*)s_c)[t]=csrc[t];
  }
  float as_h[8], as0;
  {
    const float* ap = A_log + (size_t)m*1024 + d*16;
    as0 = -expf(ap[0])*LOG2E;
    #pragma unroll
    for(int k=0;k<8;k++) as_h[k] = -expf(ap[sh8+k])*LOG2E;
  }
  bool stl = true;
  #pragma unroll
  for(int k=0;k<8;k++){ float ex=(float)(sh8+k+1)*as0; stl = stl && (fabsf(as_h[k]-ex) <= 1e-4f*fabsf(ex)); }
  const bool structured = (__ballot(stl) == ~0ull);

  const float dpv2 = (sh==0) ? Dp[m*64+d] : 0.f;

  // ---- self-combine: h0 = fold of chunk summaries 0..chunk-1 (global pb/eb, L2-resident) ----
  float h[8];
  #pragma unroll
  for(int k=0;k<8;k++) h[k]=0.f;
  {
    const float* pbase = pb + (((size_t)seq*NC)*64 + d)*16 + sh8;
    const float* ebase = eb + (((size_t)seq*NC)*64 + d)*16 + sh8;
    #pragma unroll 2
    for(int cc=0; cc<chunk; ++cc){
      const float4* pp = (const float4*)(pbase + (size_t)cc*1024);
      const float4* ee = (const float4*)(ebase + (size_t)cc*1024);
      float4 p0=pp[0], p1=pp[1], e0=ee[0], e1=ee[1];
      h[0]=fmaf(p0.x,h[0],e0.x); h[1]=fmaf(p0.y,h[1],e0.y);
      h[2]=fmaf(p0.z,h[2],e0.z); h[3]=fmaf(p0.w,h[3],e0.w);
      h[4]=fmaf(p1.x,h[4],e1.x); h[5]=fmaf(p1.y,h[5],e1.y);
      h[6]=fmaf(p1.z,h[6],e1.z); h[7]=fmaf(p1.w,h[7],e1.w);
    }
  }

  const float2* dxp=(const float2*)(dxb + ((size_t)seq*LSEQ + (size_t)chunk*LC)*128);
  float* s_yw = sh ? s_y1 : s_y0;
  __syncthreads();

  // FAST: pz[k] = q^(8sh+1+k), ONE exp2 per step
  #define CSTEPF(i_, dx_, P0CODE) { \
    float dl=dx_.x, xv=dx_.y; float u=dl*xv; \
    const float4* bq=(const float4*)(s_b + cl*(LC*NS) + (i_)*NS + sh8); \
    const float4* cq=(const float4*)(s_c + cl*(LC*NS) + (i_)*NS + sh8); \
    float4 b0=bq[0],b1=bq[1],c0=cq[0],c1=cq[1]; \
    float bb[8]={b0.x,b0.y,b0.z,b0.w, b1.x,b1.y,b1.z,b1.w}; \
    float cc2[8]={c0.x,c0.y,c0.z,c0.w, c1.x,c1.y,c1.z,c1.w}; \
    float q=fexp2(dl*as0); \
    float q2=q*q; float q4=q2*q2; (void)q2; (void)q4; \
    float pz[8]; pz[0]=(P0CODE); \
    _Pragma("unroll") for(int k=1;k<8;k++) pz[k]=pz[k-1]*q; \
    float ya=0.f, yb2=0.f; \
    _Pragma("unroll") for(int k=0;k<8;k++){ \
      h[k]=fmaf(pz[k],h[k],u*bb[k]); \
      float hv=h[k]*cc2[k]; \
      if(k&1) yb2+=hv; else ya+=hv; } \
    float y=ya+yb2; y=fmaf(dpv2,xv,y); \
    s_yw[(cl*LC+(i_))*64 + d]=y; }

  #define CSTEPG(i_, dx_) { \
    float dl=dx_.x, xv=dx_.y; float u=dl*xv; \
    const float4* bq=(const float4*)(s_b + cl*(LC*NS) + (i_)*NS + sh8); \
    const float4* cq=(const float4*)(s_c + cl*(LC*NS) + (i_)*NS + sh8); \
    float4 b0=bq[0],b1=bq[1],c0=cq[0],c1=cq[1]; \
    float bb[8]={b0.x,b0.y,b0.z,b0.w, b1.x,b1.y,b1.z,b1.w}; \
    float cc2[8]={c0.x,c0.y,c0.z,c0.w, c1.x,c1.y,c1.z,c1.w}; \
    float pz[8]; \
    _Pragma("unroll") for(int k=0;k<8;k++) pz[k]=fexp2(dl*as_h[k]); \
    float ya=0.f, yb2=0.f; \
    _Pragma("unroll") for(int k=0;k<8;k++){ \
      h[k]=fmaf(pz[k],h[k],u*bb[k]); \
      float hv=h[k]*cc2[k]; \
      if(k&1) yb2+=hv; else ya+=hv; } \
    float y=ya+yb2; y=fmaf(dpv2,xv,y); \
    s_yw[(cl*LC+(i_))*64 + d]=y; }

  #define CLOOPF(P0CODE) { \
    float2 dxw[4]; \
    _Pragma("unroll") for(int k=0;k<4;k++) dxw[k]=dxp[k*64+d]; \
    for(int ii=0;ii<LC;ii+=4){ \
      float2 c0w=dxw[0],c1w=dxw[1],c2w=dxw[2],c3w=dxw[3]; \
      if(ii+4<LC){ _Pragma("unroll") for(int k=0;k<4;k++) dxw[k]=dxp[(ii+4+k)*64+d]; } \
      CSTEPF(ii+0,c0w,P0CODE); CSTEPF(ii+1,c1w,P0CODE); \
      CSTEPF(ii+2,c2w,P0CODE); CSTEPF(ii+3,c3w,P0CODE); } }

  if(structured){
    if(sh==0){ CLOOPF(q) }
    else     { CLOOPF((q4*q4)*q) }
  } else {
    float2 dxw[4];
    #pragma unroll
    for(int k=0;k<4;k++) dxw[k]=dxp[k*64+d];
    for(int ii=0;ii<LC;ii+=4){
      float2 c0w=dxw[0],c1w=dxw[1],c2w=dxw[2],c3w=dxw[3];
      if(ii+4<LC){
        #pragma unroll
        for(int k=0;k<4;k++) dxw[k]=dxp[(ii+4+k)*64+d];
      }
      CSTEPG(ii+0,c0w); CSTEPG(ii+1,c1w); CSTEPG(ii+2,c2w); CSTEPG(ii+3,c3w);
    }
  }
  #undef CLOOPF
  #undef CSTEPF
  #undef CSTEPG

  __syncthreads();
  // gate pass: yg = (y0+y1)*silu(z), into s_y0
  {
    const float* zp = zb + ((size_t)seq*LSEQ + l0)*64;
    #pragma unroll
    for(int it=0; it<16; ++it){
      int idx = t + it*256;
      float ysum = s_y0[idx] + s_y1[idx];
      s_y0[idx] = ysum * silu_f(zp[idx]);
    }
  }
  const int o=t&31, grp=t>>5;
  float wreg[64];
  {
    const float4* wp=(const float4*)(out_w + (size_t)m*2048 + (size_t)o*64);
    #pragma unroll
    for(int k4=0;k4<16;k4++){
      float4 v=wp[k4];
      wreg[k4*4+0]=v.x; wreg[k4*4+1]=v.y; wreg[k4*4+2]=v.z; wreg[k4*4+3]=v.w;
    }
  }
  const float sk=skipv[m];
  __syncthreads();
  for(int ll=grp; ll<64; ll+=8){
    const float4* ya=(const float4*)&s_y0[ll*64];
    float a0=0.f,a1=0.f;
    #pragma unroll
    for(int k=0;k<16;k+=2){
      float4 u=ya[k], u2=ya[k+1];
      a0 += u.x *wreg[4*k+0]+u.y *wreg[4*k+1]+u.z *wreg[4*k+2]+u.w *wreg[4*k+3];
      a1 += u2.x*wreg[4*k+4]+u2.y*wreg[4*k+5]+u2.z*wreg[4*k+6]+u2.w*wreg[4*k+7];
    }
    size_t xidx=((size_t)j*LSEQ + l0+ll)*128 + p*32 + o;
    xmb[xidx]=(a0+a1) + sk*xnb[xidx];
  }
}

// ---------------- K5: LN2 + proj, both experts, 8 l per block ----------------
__global__ __launch_bounds__(256) void k5_ln2_proj(
  const int* __restrict__ did, const float* __restrict__ ln_g, const float* __restrict__ ln_b,
  const float* __restrict__ proj_w, const float* __restrict__ proj_b,
  const float* __restrict__ xmb, float* __restrict__ out)
{
  const int b=blockIdx.y, l0=blockIdx.x*8, t=threadIdx.x;
  const int eh = t>>7, local = t&127;
  const int j = 2*b+eh;
  const int m = mixer_of(did, j);
  __shared__ float s_xn[2][8][132];
  __shared__ float s_comb[8][132];
  __shared__ float s_murs[2][8][2];

  for(int idx=local; idx<1024; idx+=128){
    int ll=idx>>7, c=idx&127;
    s_xn[eh][ll][c] = xmb[((size_t)j*LSEQ + l0+ll)*128 + c];
  }
  __syncthreads();
  if(((t>>6)&1)==0){
    const int lane = t&63;
    const int g = lane&7, ll = lane>>3;
    float sum=0.f, vs=0.f;
    const float4* xr4 = (const float4*)(&s_xn[eh][ll][g*16]);
    #pragma unroll
    for(int k=0;k<4;k++){
      float4 v = xr4[k];
      sum += (v.x+v.y)+(v.z+v.w);
      vs  += v.x*v.x + v.y*v.y + v.z*v.z + v.w*v.w;
    }
    sum += __shfl_xor(sum,1); vs += __shfl_xor(vs,1);
    sum += __shfl_xor(sum,2); vs += __shfl_xor(vs,2);
    sum += __shfl_xor(sum,4); vs += __shfl_xor(vs,4);
    float mu  = sum*(1.f/128.f);
    float var = fmaxf(vs*(1.f/128.f) - mu*mu, 0.f);
    if(g==0){ s_murs[eh][ll][0]=mu; s_murs[eh][ll][1]=rsqrtf(var+1e-5f); }
  }
  __syncthreads();
  for(int idx=local; idx<1024; idx+=128){
    int ll=idx>>7, c=idx&127;
    float xn=(s_xn[eh][ll][c]-s_murs[eh][ll][0])*s_murs[eh][ll][1]*ln_g[m*128+c]+ln_b[m*128+c];
    s_xn[eh][ll][c]=xn;
  }
  __syncthreads();
  float acc[8];
  #pragma unroll
  for(int ll=0;ll<8;ll++) acc[ll]=0.f;
  {
    const float4* pw4 = (const float4*)(proj_w + (size_t)m*16384 + (size_t)local*128);
    #pragma unroll 4
    for(int c4=0;c4<32;c4++){
      float4 w = pw4[c4];
      int c = c4*4;
      #pragma unroll
      for(int ll=0;ll<8;ll++){
        acc[ll] += w.x*s_xn[eh][ll][c] + w.y*s_xn[eh][ll][c+1]
                 + w.z*s_xn[eh][ll][c+2] + w.w*s_xn[eh][ll][c+3];
      }
    }
  }
  float pb_v = proj_b[m*128+local];
  if(eh==0){
    #pragma unroll
    for(int ll=0;ll<8;ll++) s_comb[ll][local]=acc[ll]+pb_v;
  }
  __syncthreads();
  if(eh==1){
    #pragma unroll
    for(int ll=0;ll<8;ll++) s_comb[ll][local]+=acc[ll]+pb_v;
  }
  __syncthreads();
  for(int idx=t; idx<1024; idx+=256){
    int o=idx>>3, ll=idx&7;
    out[((size_t)b*128+o)*LSEQ + l0+ll] = s_comb[ll][o];
  }
}

extern "C" void kernel_launch(void* const* d_in, const int* in_sizes, int n_in,
                              void* d_out, int out_size, void* d_ws, size_t ws_size,
                              hipStream_t stream) {
  const float* x      = (const float*)d_in[0];
  const int*   did    = (const int*)d_in[1];
  const float* ln_g   = (const float*)d_in[2];
  const float* ln_b   = (const float*)d_in[3];
  const float* in_w   = (const float*)d_in[4];
  const float* conv_w = (const float*)d_in[5];
  const float* conv_b = (const float*)d_in[6];
  const float* xp_w   = (const float*)d_in[7];
  const float* dt_w   = (const float*)d_in[8];
  const float* dt_b   = (const float*)d_in[9];
  const float* A_log  = (const float*)d_in[10];
  const float* Dp     = (const float*)d_in[11];
  const float* out_w  = (const float*)d_in[12];
  const float* proj_w = (const float*)d_in[13];
  const float* proj_b = (const float*)d_in[14];
  const float* skipv  = (const float*)d_in[15];
  float* out = (float*)d_out;
  float* ws  = (float*)d_ws;

  float* xnb = ws;                                   // NJ*L*128   (2.10M f)
  float* xzr = xnb + (size_t)NJ*LSEQ*128;            // NSEQ*L*64  (4.19M f)
  float* zb  = xzr + (size_t)NSEQ*LSEQ*64;           // NSEQ*L*64  z (read-only after k1)
  float* dxb = zb  + (size_t)NSEQ*LSEQ*64;           // NSEQ*L*64*2 packed (dl,xi)
  float* bmb = dxb + (size_t)NSEQ*LSEQ*128;          // NSEQ*L*16
  float* cmb = bmb + (size_t)NSEQ*LSEQ*16;           // NSEQ*L*16
  float* xmb = cmb + (size_t)NSEQ*LSEQ*16;           // NJ*L*128
  // pb/eb read-only after k2 (k3c4 self-combines its prefix)
  float* pb  = xmb + (size_t)NJ*LSEQ*128;            // NSEQ*NC*1024 = 2.10M
  float* eb  = pb  + (size_t)NSEQ*NC*1024;           // 2.10M

  hipLaunchKernelGGL(k1_ln_inproj, dim3(LSEQ/16,NJ), dim3(256), 0, stream,
                     x,did,ln_g,ln_b,in_w,xnb,xzr,zb);
  hipLaunchKernelGGL(k2_conv_xproj_pe, dim3(NC,NSEQ), dim3(256), 0, stream,
                     did,conv_w,conv_b,xp_w,dt_w,dt_b,A_log,xzr,dxb,bmb,cmb,pb,eb);
  hipLaunchKernelGGL(k3c4_scan_outproj, dim3(NC/2,NSEQ), dim3(256), 0, stream,
                     did,A_log,Dp,dxb,bmb,cmb,zb,pb,eb,out_w,skipv,xnb,xmb);
  hipLaunchKernelGGL(k5_ln2_proj, dim3(LSEQ/8,2), dim3(256), 0, stream,
                     did,ln_g,ln_b,proj_w,proj_b,xmb,out);
}

// Round 13
// 119.362 us; speedup vs baseline: 1.7226x; 1.7226x over previous
//
#include <hip/hip_runtime.h>
#include <math.h>

#define LSEQ 4096   // D*H*W = 16*16*16
#define CIN  128
#define DI   64     // d_inner
#define NS   16     // d_state
#define NP   4      // parts
#define NJ   4      // jobs = (b, mixer) pairs
#define NSEQ 16     // NJ * NP independent mamba sequences
#define NC   128    // scan chunks
#define LC   32     // chunk length (NC*LC = LSEQ)
#define LOG2E 1.44269504f
#define LN2   0.6931471806f

__device__ __forceinline__ int mixer_of(const int* did, int j){
  if((j&1)==0) return 0;
  int d = did[j>>1];
  return 1 + (d < 1 ? d : 1);
}
// native transcendentals: v_exp_f32 / v_log_f32 / v_rcp_f32
__device__ __forceinline__ float fexp2(float x){ return __builtin_amdgcn_exp2f(x); }
__device__ __forceinline__ float silu_f(float x){
  return x*__builtin_amdgcn_rcpf(1.f + fexp2(-x*LOG2E));
}
__device__ __forceinline__ float softplus_f(float x){
  return x>20.f ? x : LN2*__builtin_amdgcn_logf(1.f + fexp2(x*LOG2E));
}

// ---------------- K1: LN1 + in_proj. 16 l per block, in-place LN, single LDS buffer ----------------
__global__ __launch_bounds__(256) void k1_ln_inproj(
  const float* __restrict__ x, const int* __restrict__ did,
  const float* __restrict__ ln_g, const float* __restrict__ ln_b,
  const float* __restrict__ in_w,
  float* __restrict__ xnb, float* __restrict__ xzr, float* __restrict__ zb)
{
  const int j = blockIdx.y, b = j>>1, t = threadIdx.x;
  const int l0 = blockIdx.x*16;
  const int m = mixer_of(did, j);
  __shared__ float s_xn[16][132];   // raw x, then normalized in place
  __shared__ float s_mu[16], s_rs[16];

  #pragma unroll
  for(int rep=0; rep<2; rep++){
    int fidx = t + rep*256;          // [0,512)
    int c = fidx>>2, fq = fidx&3;    // 128 c x 4 float4 (16 l)
    float4 v = *(const float4*)(x + ((size_t)b*CIN+c)*LSEQ + l0 + fq*4);
    s_xn[fq*4+0][c]=v.x; s_xn[fq*4+1][c]=v.y; s_xn[fq*4+2][c]=v.z; s_xn[fq*4+3][c]=v.w;
  }
  float wreg[32];
  {
    const float4* wp = (const float4*)(in_w + (size_t)m*4096 + (size_t)(t&127)*32);
    #pragma unroll
    for(int i=0;i<8;i++){
      float4 v = wp[i];
      wreg[i*4+0]=v.x; wreg[i*4+1]=v.y; wreg[i*4+2]=v.z; wreg[i*4+3]=v.w;
    }
  }
  __syncthreads();

  {
    const int wv = t>>6, lane = t&63;
    if(wv < 2){
      const int lw = lane&7, g = lane>>3;
      const int ll = wv*8 + lw;
      const float4* xr4 = (const float4*)(&s_xn[ll][g*16]);
      float sum=0.f, vs=0.f;
      #pragma unroll
      for(int k=0;k<4;k++){
        float4 v = xr4[k];
        sum += (v.x+v.y)+(v.z+v.w);
        vs  += v.x*v.x + v.y*v.y + v.z*v.z + v.w*v.w;
      }
      sum += __shfl_xor(sum,8);  vs += __shfl_xor(vs,8);
      sum += __shfl_xor(sum,16); vs += __shfl_xor(vs,16);
      sum += __shfl_xor(sum,32); vs += __shfl_xor(vs,32);
      float mu  = sum*(1.f/128.f);
      float var = fmaxf(vs*(1.f/128.f) - mu*mu, 0.f);
      if(g==0){ s_mu[ll]=mu; s_rs[ll]=rsqrtf(var+1e-5f); }
    }
  }
  __syncthreads();

  #pragma unroll
  for(int rep=0; rep<8; rep++){
    int idx = t + rep*256;           // [0,2048)
    int ll = idx>>7, c = idx&127;
    float xn = (s_xn[ll][c]-s_mu[ll])*s_rs[ll]*ln_g[m*128+c] + ln_b[m*128+c];
    s_xn[ll][c] = xn;
    xnb[((size_t)j*LSEQ + l0+ll)*128 + c] = xn;
  }
  __syncthreads();

  const int e = t&127, hh = t>>7;
  for(int ll=hh*8; ll<hh*8+8; ++ll){
    #pragma unroll
    for(int q=0;q<4;q++){
      const float4* xr4 = (const float4*)(&s_xn[ll][q*32]);
      float acc=0.f;
      #pragma unroll
      for(int k4=0;k4<8;k4++){
        float4 xv = xr4[k4];
        acc += xv.x*wreg[k4*4+0] + xv.y*wreg[k4*4+1]
             + xv.z*wreg[k4*4+2] + xv.w*wreg[k4*4+3];
      }
      size_t base = ((size_t)(j*NP+q)*LSEQ + l0+ll)*64;
      if(e<64) xzr[base+e]=acc; else zb[base+e-64]=acc;
    }
  }
}

// ---- K2: conv + SiLU + x_proj(all-lane) + dt/softplus + fused chunk summary (P,E) ----
__global__ __launch_bounds__(256) void k2_conv_xproj_pe(
  const int* __restrict__ did,
  const float* __restrict__ conv_w, const float* __restrict__ conv_b,
  const float* __restrict__ xp_w, const float* __restrict__ dt_w, const float* __restrict__ dt_b,
  const float* __restrict__ A_log,
  const float* __restrict__ xzr, float* __restrict__ dxb,
  float* __restrict__ bmb, float* __restrict__ cmb,
  float* __restrict__ pb, float* __restrict__ eb)
{
  const int seq = blockIdx.y, j = seq>>2, t = threadIdx.x;
  const int chunk = blockIdx.x;
  const int l0 = chunk*32;
  const int m = mixer_of(did, j);
  const int d = t&63, r = t>>6;
  __shared__ float  s_xi[32][64];
  __shared__ float  s_dl[32][64];
  __shared__ float  s_bS[32][16];
  __shared__ float  s_dbc[32][2];
  __shared__ float  s_cwT[4][64];
  __shared__ float  s_xpw01[2][64];
  __shared__ float  s_cb[64], s_dtw[128], s_dtb[64];

  float lz[11];
  #pragma unroll
  for(int i=0;i<11;i++){
    int l = l0 + r*8 - 3 + i;
    lz[i] = (l>=0) ? xzr[((size_t)seq*LSEQ + l)*64 + d] : 0.f;
  }
  { int k=t>>6, dd=t&63; s_cwT[k][dd]=conv_w[m*256+dd*4+k]; }
  if(t<64){ s_cb[t]=conv_b[m*64+t]; s_dtb[t]=dt_b[m*64+t]; }
  if(t<128){ s_dtw[t]=dt_w[m*128+t]; s_xpw01[t>>6][t&63]=xp_w[m*2176 + t]; }
  const int o2 = t&31, rg = t>>5;
  float wreg[64];
  {
    const float4* wp = (const float4*)(xp_w + (size_t)m*2176 + (size_t)(2+o2)*64);
    #pragma unroll
    for(int k4=0;k4<16;k4++){
      float4 v = wp[k4];
      wreg[k4*4+0]=v.x; wreg[k4*4+1]=v.y; wreg[k4*4+2]=v.z; wreg[k4*4+3]=v.w;
    }
  }
  __syncthreads();

  float xir[8];
  {
    float cw0=s_cwT[0][d], cw1=s_cwT[1][d], cw2=s_cwT[2][d], cw3=s_cwT[3][d], cb=s_cb[d];
    #pragma unroll
    for(int i=0;i<8;i++){
      float xc = cb + lz[i]*cw0 + lz[i+1]*cw1 + lz[i+2]*cw2 + lz[i+3]*cw3;
      xir[i] = silu_f(xc);
      s_xi[r*8+i][d] = xir[i];
    }
  }

  {
    float pr[8];
    #pragma unroll
    for(int i=0;i<8;i++){
      float p0 = xir[i]*s_xpw01[0][d];
      float p1 = xir[i]*s_xpw01[1][d];
      float q0 = p0 + __shfl_xor(p0,1);
      float q1 = p1 + __shfl_xor(p1,1);
      pr[i] = (d&1) ? q1 : q0;
    }
    #pragma unroll
    for(int off=2; off<64; off<<=1){
      #pragma unroll
      for(int i=0;i<8;i++) pr[i] += __shfl_xor(pr[i], off);
    }
    if(d<2){
      #pragma unroll
      for(int i=0;i<8;i++) s_dbc[r*8+i][d] = pr[i];
    }
  }
  __syncthreads();

  {
    float w0=s_dtw[d*2], w1=s_dtw[d*2+1], bb=s_dtb[d];
    #pragma unroll
    for(int i=0;i<8;i++){
      int ll=r*8+i;
      float dtv = s_dbc[ll][0]*w0 + s_dbc[ll][1]*w1 + bb;
      float dlv = softplus_f(dtv);
      s_dl[ll][d] = dlv;
      *(float2*)(dxb + ((size_t)seq*LSEQ + l0+ll)*128 + d*2) = make_float2(dlv, xir[i]);
    }
  }

  {
    #pragma unroll
    for(int ip=0; ip<2; ip++){
      int ll = rg*4 + ip*2;
      const float4* xa=(const float4*)&s_xi[ll][0];
      const float4* xb=(const float4*)&s_xi[ll+1][0];
      float a0=0.f,a1=0.f,b0=0.f,b1=0.f;
      #pragma unroll
      for(int k=0;k<16;k+=2){
        float4 u=xa[k], u2=xa[k+1], v=xb[k], v2=xb[k+1];
        a0 += u.x *wreg[4*k+0]+u.y *wreg[4*k+1]+u.z *wreg[4*k+2]+u.w *wreg[4*k+3];
        a1 += u2.x*wreg[4*k+4]+u2.y*wreg[4*k+5]+u2.z*wreg[4*k+6]+u2.w*wreg[4*k+7];
        b0 += v.x *wreg[4*k+0]+v.y *wreg[4*k+1]+v.z *wreg[4*k+2]+v.w *wreg[4*k+3];
        b1 += v2.x*wreg[4*k+4]+v2.y*wreg[4*k+5]+v2.z*wreg[4*k+6]+v2.w*wreg[4*k+7];
      }
      float A=a0+a1, Bv=b0+b1;
      if(o2<16){
        s_bS[ll][o2]=A; s_bS[ll+1][o2]=Bv;
        bmb[((size_t)seq*LSEQ + l0+ll  )*16 + o2]=A;
        bmb[((size_t)seq*LSEQ + l0+ll+1)*16 + o2]=Bv;
      } else {
        cmb[((size_t)seq*LSEQ + l0+ll  )*16 + o2-16]=A;
        cmb[((size_t)seq*LSEQ + l0+ll+1)*16 + o2-16]=Bv;
      }
    }
  }
  __syncthreads();

  // ---- fused chunk summary: thread = (d, s-quad sq=r), 4 states each ----
  {
    const int sq = r;              // wave-uniform
    float as_q[4], as0;
    {
      const float* ap = A_log + (size_t)m*1024 + d*16;
      as0 = -expf(ap[0])*LOG2E;
      #pragma unroll
      for(int k=0;k<4;k++) as_q[k] = -expf(ap[sq*4+k])*LOG2E;
    }
    bool stl = true;
    #pragma unroll
    for(int k=0;k<4;k++){ float ex=(float)(sq*4+k+1)*as0; stl = stl && (fabsf(as_q[k]-ex) <= 1e-4f*fabsf(ex)); }
    const bool structured = (__ballot(stl) == ~0ull);

    float E[4] = {0.f,0.f,0.f,0.f};
    float Sdl = 0.f;

    // FAST: p_k = q^(4sq+1+k), q = exp2(dl*as0). ONE exp2 per step.
    #define PSTEPF(i_, P0CODE) { \
      float dl = s_dl[i_][d]; \
      float u  = dl * s_xi[i_][d]; \
      Sdl += dl; \
      const float4 bv = *(const float4*)(&s_bS[i_][sq*4]); \
      float q = fexp2(dl*as0); \
      float q2 = q*q; float q4 = q2*q2; (void)q2; (void)q4; \
      float p0 = (P0CODE); \
      float p1 = p0*q, p2 = p1*q, p3 = p2*q; \
      E[0]=fmaf(p0,E[0],u*bv.x); E[1]=fmaf(p1,E[1],u*bv.y); \
      E[2]=fmaf(p2,E[2],u*bv.z); E[3]=fmaf(p3,E[3],u*bv.w); }

    #define PSTEPG(i_) { \
      float dl = s_dl[i_][d]; \
      float u  = dl * s_xi[i_][d]; \
      Sdl += dl; \
      const float4 bv = *(const float4*)(&s_bS[i_][sq*4]); \
      float p_[4]; \
      _Pragma("unroll") for(int k=0;k<4;k++) p_[k]=fexp2(dl*as_q[k]); \
      E[0]=fmaf(p_[0],E[0],u*bv.x); E[1]=fmaf(p_[1],E[1],u*bv.y); \
      E[2]=fmaf(p_[2],E[2],u*bv.z); E[3]=fmaf(p_[3],E[3],u*bv.w); }

    if(structured){
      if(sq==0){
        #pragma unroll 4
        for(int i=0;i<LC;i++){ PSTEPF(i, q) }
      } else if(sq==1){
        #pragma unroll 4
        for(int i=0;i<LC;i++){ PSTEPF(i, q4*q) }
      } else if(sq==2){
        #pragma unroll 4
        for(int i=0;i<LC;i++){ PSTEPF(i, (q4*q4)*q) }
      } else {
        #pragma unroll 4
        for(int i=0;i<LC;i++){ PSTEPF(i, ((q4*q4)*q4)*q) }
      }
    } else {
      #pragma unroll 4
      for(int i=0;i<LC;i++){ PSTEPG(i) }
    }
    #undef PSTEPF
    #undef PSTEPG

    size_t oo=(((size_t)seq*NC+chunk)*64+d)*16 + sq*4;
    *(float4*)(pb+oo) = make_float4(fexp2(Sdl*as_q[0]),fexp2(Sdl*as_q[1]),
                                    fexp2(Sdl*as_q[2]),fexp2(Sdl*as_q[3]));
    *(float4*)(eb+oo) = make_float4(E[0],E[1],E[2],E[3]);
  }
}

// ---------------- K3b: combine chunk summaries, batched prefetch; hs written in-place into p ----------------
__global__ __launch_bounds__(256) void k3b_combine(
  float* p_hs, const float* __restrict__ eb)
{
  const int seq=blockIdx.y, q=blockIdx.x, t=threadIdx.x;
  const size_t elem = (size_t)q*256+t;
  #define OFF(c_) (((size_t)seq*NC+(c_))*1024 + elem)
  float pA[16],eA[16],pB[16],eB[16];
  #pragma unroll
  for(int k=0;k<16;k++){ pA[k]=p_hs[OFF(k)]; eA[k]=eb[OFF(k)]; }
  float h=0.f;
  for(int bt=0; bt<8; bt+=2){
    if(bt+1<8){
      #pragma unroll
      for(int k=0;k<16;k++){ pB[k]=p_hs[OFF((bt+1)*16+k)]; eB[k]=eb[OFF((bt+1)*16+k)]; }
    }
    #pragma unroll
    for(int k=0;k<16;k++){ p_hs[OFF(bt*16+k)]=h; h=fmaf(pA[k],h,eA[k]); }
    if(bt+2<8){
      #pragma unroll
      for(int k=0;k<16;k++){ pA[k]=p_hs[OFF((bt+2)*16+k)]; eA[k]=eb[OFF((bt+2)*16+k)]; }
    }
    #pragma unroll
    for(int k=0;k<16;k++){ p_hs[OFF((bt+1)*16+k)]=h; h=fmaf(pB[k],h,eB[k]); }
  }
  #undef OFF
}

// -------- K3C4: rescan + gate + out_proj + skip. 2 chunks x 2 s-half waves, y planes in LDS --------
__global__ __launch_bounds__(256) void k3c4_scan_outproj(
  const int* __restrict__ did, const float* __restrict__ A_log, const float* __restrict__ Dp,
  const float* __restrict__ dxb,
  const float* __restrict__ bmb, const float* __restrict__ cmb,
  const float* __restrict__ zb, const float* __restrict__ hsb,
  const float* __restrict__ out_w, const float* __restrict__ skipv,
  const float* __restrict__ xnb, float* __restrict__ xmb)
{
  const int seq=blockIdx.y, j=seq>>2, p=seq&3, t=threadIdx.x;
  const int wave=t>>6, d=t&63;
  const int cl=wave>>1, sh=wave&1, sh8=sh*8;
  const int chunk=blockIdx.x*2+cl;
  const int l0=blockIdx.x*2*LC;            // 64 l per block
  const int m=mixer_of(did,j);
  __shared__ float s_b[2*LC*NS];           // 4KB
  __shared__ float s_c[2*LC*NS];           // 4KB
  __shared__ float s_y0[64*64];            // 16KB
  __shared__ float s_y1[64*64];            // 16KB
  {
    const float4* bsrc=(const float4*)(bmb + ((size_t)seq*LSEQ + l0)*NS);
    const float4* csrc=(const float4*)(cmb + ((size_t)seq*LSEQ + l0)*NS);
    ((float4*)s_b)[t]=bsrc[t];
    ((float4*)s_c)[t]=csrc[t];
  }
  float as_h[8], as0;
  {
    const float* ap = A_log + (size_t)m*1024 + d*16;
    as0 = -expf(ap[0])*LOG2E;
    #pragma unroll
    for(int k=0;k<8;k++) as_h[k] = -expf(ap[sh8+k])*LOG2E;
  }
  bool stl = true;
  #pragma unroll
  for(int k=0;k<8;k++){ float ex=(float)(sh8+k+1)*as0; stl = stl && (fabsf(as_h[k]-ex) <= 1e-4f*fabsf(ex)); }
  const bool structured = (__ballot(stl) == ~0ull);

  const float dpv2 = (sh==0) ? Dp[m*64+d] : 0.f;
  float h[8];
  {
    const float4* hp=(const float4*)(hsb + (((size_t)seq*NC+chunk)*64+d)*16 + sh8);
    float4 v0=hp[0], v1=hp[1];
    h[0]=v0.x; h[1]=v0.y; h[2]=v0.z; h[3]=v0.w;
    h[4]=v1.x; h[5]=v1.y; h[6]=v1.z; h[7]=v1.w;
  }
  const float2* dxp=(const float2*)(dxb + ((size_t)seq*LSEQ + (size_t)chunk*LC)*128);
  float* s_yw = sh ? s_y1 : s_y0;
  __syncthreads();

  // FAST: pz[k] = q^(8sh+1+k), ONE exp2 per step
  #define CSTEPF(i_, dx_, P0CODE) { \
    float dl=dx_.x, xv=dx_.y; float u=dl*xv; \
    const float4* bq=(const float4*)(s_b + cl*(LC*NS) + (i_)*NS + sh8); \
    const float4* cq=(const float4*)(s_c + cl*(LC*NS) + (i_)*NS + sh8); \
    float4 b0=bq[0],b1=bq[1],c0=cq[0],c1=cq[1]; \
    float bb[8]={b0.x,b0.y,b0.z,b0.w, b1.x,b1.y,b1.z,b1.w}; \
    float cc2[8]={c0.x,c0.y,c0.z,c0.w, c1.x,c1.y,c1.z,c1.w}; \
    float q=fexp2(dl*as0); \
    float q2=q*q; float q4=q2*q2; (void)q2; (void)q4; \
    float pz[8]; pz[0]=(P0CODE); \
    _Pragma("unroll") for(int k=1;k<8;k++) pz[k]=pz[k-1]*q; \
    float ya=0.f, yb2=0.f; \
    _Pragma("unroll") for(int k=0;k<8;k++){ \
      h[k]=fmaf(pz[k],h[k],u*bb[k]); \
      float hv=h[k]*cc2[k]; \
      if(k&1) yb2+=hv; else ya+=hv; } \
    float y=ya+yb2; y=fmaf(dpv2,xv,y); \
    s_yw[(cl*LC+(i_))*64 + d]=y; }

  #define CSTEPG(i_, dx_) { \
    float dl=dx_.x, xv=dx_.y; float u=dl*xv; \
    const float4* bq=(const float4*)(s_b + cl*(LC*NS) + (i_)*NS + sh8); \
    const float4* cq=(const float4*)(s_c + cl*(LC*NS) + (i_)*NS + sh8); \
    float4 b0=bq[0],b1=bq[1],c0=cq[0],c1=cq[1]; \
    float bb[8]={b0.x,b0.y,b0.z,b0.w, b1.x,b1.y,b1.z,b1.w}; \
    float cc2[8]={c0.x,c0.y,c0.z,c0.w, c1.x,c1.y,c1.z,c1.w}; \
    float pz[8]; \
    _Pragma("unroll") for(int k=0;k<8;k++) pz[k]=fexp2(dl*as_h[k]); \
    float ya=0.f, yb2=0.f; \
    _Pragma("unroll") for(int k=0;k<8;k++){ \
      h[k]=fmaf(pz[k],h[k],u*bb[k]); \
      float hv=h[k]*cc2[k]; \
      if(k&1) yb2+=hv; else ya+=hv; } \
    float y=ya+yb2; y=fmaf(dpv2,xv,y); \
    s_yw[(cl*LC+(i_))*64 + d]=y; }

  #define CLOOPF(P0CODE) { \
    float2 dxw[4]; \
    _Pragma("unroll") for(int k=0;k<4;k++) dxw[k]=dxp[k*64+d]; \
    for(int ii=0;ii<LC;ii+=4){ \
      float2 c0w=dxw[0],c1w=dxw[1],c2w=dxw[2],c3w=dxw[3]; \
      if(ii+4<LC){ _Pragma("unroll") for(int k=0;k<4;k++) dxw[k]=dxp[(ii+4+k)*64+d]; } \
      CSTEPF(ii+0,c0w,P0CODE); CSTEPF(ii+1,c1w,P0CODE); \
      CSTEPF(ii+2,c2w,P0CODE); CSTEPF(ii+3,c3w,P0CODE); } }

  if(structured){
    if(sh==0){ CLOOPF(q) }
    else     { CLOOPF((q4*q4)*q) }
  } else {
    float2 dxw[4];
    #pragma unroll
    for(int k=0;k<4;k++) dxw[k]=dxp[k*64+d];
    for(int ii=0;ii<LC;ii+=4){
      float2 c0w=dxw[0],c1w=dxw[1],c2w=dxw[2],c3w=dxw[3];
      if(ii+4<LC){
        #pragma unroll
        for(int k=0;k<4;k++) dxw[k]=dxp[(ii+4+k)*64+d];
      }
      CSTEPG(ii+0,c0w); CSTEPG(ii+1,c1w); CSTEPG(ii+2,c2w); CSTEPG(ii+3,c3w);
    }
  }
  #undef CLOOPF
  #undef CSTEPF
  #undef CSTEPG

  __syncthreads();
  // gate pass: yg = (y0+y1)*silu(z), into s_y0
  {
    const float* zp = zb + ((size_t)seq*LSEQ + l0)*64;
    #pragma unroll
    for(int it=0; it<16; ++it){
      int idx = t + it*256;
      float ysum = s_y0[idx] + s_y1[idx];
      s_y0[idx] = ysum * silu_f(zp[idx]);
    }
  }
  const int o=t&31, grp=t>>5;
  float wreg[64];
  {
    const float4* wp=(const float4*)(out_w + (size_t)m*2048 + (size_t)o*64);
    #pragma unroll
    for(int k4=0;k4<16;k4++){
      float4 v=wp[k4];
      wreg[k4*4+0]=v.x; wreg[k4*4+1]=v.y; wreg[k4*4+2]=v.z; wreg[k4*4+3]=v.w;
    }
  }
  const float sk=skipv[m];
  __syncthreads();
  for(int ll=grp; ll<64; ll+=8){
    const float4* ya=(const float4*)&s_y0[ll*64];
    float a0=0.f,a1=0.f;
    #pragma unroll
    for(int k=0;k<16;k+=2){
      float4 u=ya[k], u2=ya[k+1];
      a0 += u.x *wreg[4*k+0]+u.y *wreg[4*k+1]+u.z *wreg[4*k+2]+u.w *wreg[4*k+3];
      a1 += u2.x*wreg[4*k+4]+u2.y*wreg[4*k+5]+u2.z*wreg[4*k+6]+u2.w*wreg[4*k+7];
    }
    size_t xidx=((size_t)j*LSEQ + l0+ll)*128 + p*32 + o;
    xmb[xidx]=(a0+a1) + sk*xnb[xidx];
  }
}

// ---------------- K5: LN2 + proj, both experts, 8 l per block ----------------
__global__ __launch_bounds__(256) void k5_ln2_proj(
  const int* __restrict__ did, const float* __restrict__ ln_g, const float* __restrict__ ln_b,
  const float* __restrict__ proj_w, const float* __restrict__ proj_b,
  const float* __restrict__ xmb, float* __restrict__ out)
{
  const int b=blockIdx.y, l0=blockIdx.x*8, t=threadIdx.x;
  const int eh = t>>7, local = t&127;
  const int j = 2*b+eh;
  const int m = mixer_of(did, j);
  __shared__ float s_xn[2][8][132];
  __shared__ float s_comb[8][132];
  __shared__ float s_murs[2][8][2];

  for(int idx=local; idx<1024; idx+=128){
    int ll=idx>>7, c=idx&127;
    s_xn[eh][ll][c] = xmb[((size_t)j*LSEQ + l0+ll)*128 + c];
  }
  __syncthreads();
  if(((t>>6)&1)==0){
    const int lane = t&63;
    const int g = lane&7, ll = lane>>3;
    float sum=0.f, vs=0.f;
    const float4* xr4 = (const float4*)(&s_xn[eh][ll][g*16]);
    #pragma unroll
    for(int k=0;k<4;k++){
      float4 v = xr4[k];
      sum += (v.x+v.y)+(v.z+v.w);
      vs  += v.x*v.x + v.y*v.y + v.z*v.z + v.w*v.w;
    }
    sum += __shfl_xor(sum,1); vs += __shfl_xor(vs,1);
    sum += __shfl_xor(sum,2); vs += __shfl_xor(vs,2);
    sum += __shfl_xor(sum,4); vs += __shfl_xor(vs,4);
    float mu  = sum*(1.f/128.f);
    float var = fmaxf(vs*(1.f/128.f) - mu*mu, 0.f);
    if(g==0){ s_murs[eh][ll][0]=mu; s_murs[eh][ll][1]=rsqrtf(var+1e-5f); }
  }
  __syncthreads();
  for(int idx=local; idx<1024; idx+=128){
    int ll=idx>>7, c=idx&127;
    float xn=(s_xn[eh][ll][c]-s_murs[eh][ll][0])*s_murs[eh][ll][1]*ln_g[m*128+c]+ln_b[m*128+c];
    s_xn[eh][ll][c]=xn;
  }
  __syncthreads();
  float acc[8];
  #pragma unroll
  for(int ll=0;ll<8;ll++) acc[ll]=0.f;
  {
    const float4* pw4 = (const float4*)(proj_w + (size_t)m*16384 + (size_t)local*128);
    #pragma unroll 4
    for(int c4=0;c4<32;c4++){
      float4 w = pw4[c4];
      int c = c4*4;
      #pragma unroll
      for(int ll=0;ll<8;ll++){
        acc[ll] += w.x*s_xn[eh][ll][c] + w.y*s_xn[eh][ll][c+1]
                 + w.z*s_xn[eh][ll][c+2] + w.w*s_xn[eh][ll][c+3];
      }
    }
  }
  float pb_v = proj_b[m*128+local];
  if(eh==0){
    #pragma unroll
    for(int ll=0;ll<8;ll++) s_comb[ll][local]=acc[ll]+pb_v;
  }
  __syncthreads();
  if(eh==1){
    #pragma unroll
    for(int ll=0;ll<8;ll++) s_comb[ll][local]+=acc[ll]+pb_v;
  }
  __syncthreads();
  for(int idx=t; idx<1024; idx+=256){
    int o=idx>>3, ll=idx&7;
    out[((size_t)b*128+o)*LSEQ + l0+ll] = s_comb[ll][o];
  }
}

extern "C" void kernel_launch(void* const* d_in, const int* in_sizes, int n_in,
                              void* d_out, int out_size, void* d_ws, size_t ws_size,
                              hipStream_t stream) {
  const float* x      = (const float*)d_in[0];
  const int*   did    = (const int*)d_in[1];
  const float* ln_g   = (const float*)d_in[2];
  const float* ln_b   = (const float*)d_in[3];
  const float* in_w   = (const float*)d_in[4];
  const float* conv_w = (const float*)d_in[5];
  const float* conv_b = (const float*)d_in[6];
  const float* xp_w   = (const float*)d_in[7];
  const float* dt_w   = (const float*)d_in[8];
  const float* dt_b   = (const float*)d_in[9];
  const float* A_log  = (const float*)d_in[10];
  const float* Dp     = (const float*)d_in[11];
  const float* out_w  = (const float*)d_in[12];
  const float* proj_w = (const float*)d_in[13];
  const float* proj_b = (const float*)d_in[14];
  const float* skipv  = (const float*)d_in[15];
  float* out = (float*)d_out;
  float* ws  = (float*)d_ws;

  float* xnb = ws;                                   // NJ*L*128   (2.10M f)
  float* xzr = xnb + (size_t)NJ*LSEQ*128;            // NSEQ*L*64  (4.19M f)
  float* zb  = xzr + (size_t)NSEQ*LSEQ*64;           // NSEQ*L*64  z (read-only after k1)
  float* dxb = zb  + (size_t)NSEQ*LSEQ*64;           // NSEQ*L*64*2 packed (dl,xi)
  float* bmb = dxb + (size_t)NSEQ*LSEQ*128;          // NSEQ*L*16
  float* cmb = bmb + (size_t)NSEQ*LSEQ*16;           // NSEQ*L*16
  float* xmb = cmb + (size_t)NSEQ*LSEQ*16;           // NJ*L*128
  // pb/eb disjoint from xzr (k2 reads xzr while writing pb/eb); hs in-place in pb via k3b
  float* pb  = xmb + (size_t)NJ*LSEQ*128;            // NSEQ*NC*1024 = 2.10M
  float* eb  = pb  + (size_t)NSEQ*NC*1024;           // 2.10M
  float* hsb = pb;

  hipLaunchKernelGGL(k1_ln_inproj, dim3(LSEQ/16,NJ), dim3(256), 0, stream,
                     x,did,ln_g,ln_b,in_w,xnb,xzr,zb);
  hipLaunchKernelGGL(k2_conv_xproj_pe, dim3(NC,NSEQ), dim3(256), 0, stream,
                     did,conv_w,conv_b,xp_w,dt_w,dt_b,A_log,xzr,dxb,bmb,cmb,pb,eb);
  hipLaunchKernelGGL(k3b_combine, dim3(4,NSEQ), dim3(256), 0, stream, pb,eb);
  hipLaunchKernelGGL(k3c4_scan_outproj, dim3(NC/2,NSEQ), dim3(256), 0, stream,
                     did,A_log,Dp,dxb,bmb,cmb,zb,hsb,out_w,skipv,xnb,xmb);
  hipLaunchKernelGGL(k5_ln2_proj, dim3(LSEQ/8,2), dim3(256), 0, stream,
                     did,ln_g,ln_b,proj_w,proj_b,xmb,out);
}

// Round 14
// 119.113 us; speedup vs baseline: 1.7262x; 1.0021x over previous
//
#include <hip/hip_runtime.h>
#include <math.h>

#define LSEQ 4096   // D*H*W = 16*16*16
#define CIN  128
#define DI   64     // d_inner
#define NS   16     // d_state
#define NP   4      // parts
#define NJ   4      // jobs = (b, mixer) pairs
#define NSEQ 16     // NJ * NP independent mamba sequences
#define NC   128    // scan chunks
#define LC   32     // chunk length (NC*LC = LSEQ)
#define LOG2E 1.44269504f
#define LN2   0.6931471806f

__device__ __forceinline__ int mixer_of(const int* did, int j){
  if((j&1)==0) return 0;
  int d = did[j>>1];
  return 1 + (d < 1 ? d : 1);
}
// native transcendentals: v_exp_f32 / v_log_f32 / v_rcp_f32
__device__ __forceinline__ float fexp2(float x){ return __builtin_amdgcn_exp2f(x); }
__device__ __forceinline__ float silu_f(float x){
  return x*__builtin_amdgcn_rcpf(1.f + fexp2(-x*LOG2E));
}
__device__ __forceinline__ float softplus_f(float x){
  return x>20.f ? x : LN2*__builtin_amdgcn_logf(1.f + fexp2(x*LOG2E));
}

// ==== K12: LN1 + in_proj + conv + SiLU + x_proj + dt/softplus + chunk summary (P,E), fused ====
// block = (chunk, seq). Stages x rows l0-4..l0+31, computes LN locally (identical across the
// 4 part-blocks of a job; each writes its own 32-ch slice of xnb/zb), in_proj in-LDS, then
// the former k2 pipeline reading xi from LDS.
__global__ __launch_bounds__(256) void k12_fused(
  const float* __restrict__ x, const int* __restrict__ did,
  const float* __restrict__ ln_g, const float* __restrict__ ln_b,
  const float* __restrict__ in_w,
  const float* __restrict__ conv_w, const float* __restrict__ conv_b,
  const float* __restrict__ xp_w, const float* __restrict__ dt_w, const float* __restrict__ dt_b,
  const float* __restrict__ A_log,
  float* __restrict__ xnb, float* __restrict__ zb, float* __restrict__ dxb,
  float* __restrict__ bmb, float* __restrict__ cmb,
  float* __restrict__ pb, float* __restrict__ eb)
{
  const int seq = blockIdx.y, j = seq>>2, q = seq&3, b = j>>1;
  const int chunk = blockIdx.x, l0 = chunk*32;
  const int m = mixer_of(did, j);
  const int t = threadIdx.x, d = t&63, r = t>>6;

  __shared__ float s_x[36*132];      // 19008B: raw x rows l0-4..l0+31; later aliased s_xi/s_dl
  __shared__ float s_xn[36][36];     // normalized 32-ch slice (rows 1..35 used), 16B-aligned rows
  __shared__ float s_xzf[35][64];    // xi pre-conv, rows l0-3..l0+31
  __shared__ float s_bS[32][16];
  __shared__ float s_dbc[32][2];
  __shared__ float s_cwT[4][64];
  __shared__ float s_xpw01[2][64];
  __shared__ float s_cb[64], s_dtw[128], s_dtb[64];
  __shared__ float s_mu[36], s_rs[36];
  float* s_xi = s_x;                 // [32][64] alias (s_x dead after normalize)
  float* s_dl = s_x + 2048;          // [32][64] alias

  // ---- stage x (float4 along l; row i = l0-4+i) ----
  for(int idx=t; idx<1152; idx+=256){
    int c = idx/9, f = idx - c*9;
    int l = l0 - 4 + f*4;
    float4 v;
    if(l >= 0) v = *(const float4*)(x + ((size_t)b*CIN + c)*LSEQ + l);
    else       v = make_float4(0.f,0.f,0.f,0.f);
    s_x[(f*4+0)*132 + c] = v.x;
    s_x[(f*4+1)*132 + c] = v.y;
    s_x[(f*4+2)*132 + c] = v.z;
    s_x[(f*4+3)*132 + c] = v.w;
  }
  // weights (overlap with staging)
  float wreg_in[32];
  {
    const float4* wp = (const float4*)(in_w + (size_t)m*4096 + (size_t)(t&127)*32);
    #pragma unroll
    for(int i=0;i<8;i++){
      float4 v = wp[i];
      wreg_in[i*4+0]=v.x; wreg_in[i*4+1]=v.y; wreg_in[i*4+2]=v.z; wreg_in[i*4+3]=v.w;
    }
  }
  { int k=t>>6, dd=t&63; s_cwT[k][dd]=conv_w[m*256+dd*4+k]; }
  if(t<64){ s_cb[t]=conv_b[m*64+t]; s_dtb[t]=dt_b[m*64+t]; }
  if(t<128){ s_dtw[t]=dt_w[m*128+t]; s_xpw01[t>>6][t&63]=xp_w[m*2176 + t]; }
  __syncthreads();

  // ---- LN stats, rows 0..35 (fused sum/sumsq; 8-lane groups per row) ----
  {
    const int lane=t&63, g=lane&7, lw=lane>>3;
    {
      int row = r*8 + lw;                 // 0..31
      const float4* xr4 = (const float4*)(s_x + row*132 + g*16);
      float sum=0.f, vs=0.f;
      #pragma unroll
      for(int k=0;k<4;k++){
        float4 v = xr4[k];
        sum += (v.x+v.y)+(v.z+v.w);
        vs  += v.x*v.x + v.y*v.y + v.z*v.z + v.w*v.w;
      }
      sum += __shfl_xor(sum,1); vs += __shfl_xor(vs,1);
      sum += __shfl_xor(sum,2); vs += __shfl_xor(vs,2);
      sum += __shfl_xor(sum,4); vs += __shfl_xor(vs,4);
      float mu  = sum*(1.f/128.f);
      float var = fmaxf(vs*(1.f/128.f) - mu*mu, 0.f);
      if(g==0){ s_mu[row]=mu; s_rs[row]=rsqrtf(var+1e-5f); }
    }
    if(r==0 && lw<4){                     // rows 32..35
      int row = 32 + lw;
      const float4* xr4 = (const float4*)(s_x + row*132 + g*16);
      float sum=0.f, vs=0.f;
      #pragma unroll
      for(int k=0;k<4;k++){
        float4 v = xr4[k];
        sum += (v.x+v.y)+(v.z+v.w);
        vs  += v.x*v.x + v.y*v.y + v.z*v.z + v.w*v.w;
      }
      sum += __shfl_xor(sum,1); vs += __shfl_xor(vs,1);
      sum += __shfl_xor(sum,2); vs += __shfl_xor(vs,2);
      sum += __shfl_xor(sum,4); vs += __shfl_xor(vs,4);
      float mu  = sum*(1.f/128.f);
      float var = fmaxf(vs*(1.f/128.f) - mu*mu, 0.f);
      if(g==0){ s_mu[row]=mu; s_rs[row]=rsqrtf(var+1e-5f); }
    }
  }
  __syncthreads();

  // ---- normalize rows 1..35, 32-ch slice q; write xnb slice for rows 4..35 ----
  for(int idx=t; idx<1120; idx+=256){
    int row = (idx>>5) + 1, cc = idx&31;
    float xv = s_x[row*132 + q*32 + cc];
    float xn = (xv - s_mu[row])*s_rs[row]*ln_g[m*128 + q*32+cc] + ln_b[m*128 + q*32+cc];
    s_xn[row][cc] = xn;
    if(row>=4) xnb[((size_t)j*LSEQ + l0+row-4)*128 + q*32+cc] = xn;
  }
  __syncthreads();

  // ---- in_proj: e<64 -> xi rows 1..35 (to s_xzf); e>=64 -> z rows 4..35 (to zb) ----
  {
    const int e = t&127, hh = t>>7;
    if(e < 64){
      int r0 = 1 + hh*18, r1 = hh ? 36 : 19;
      for(int row=r0; row<r1; ++row){
        const float4* xr4 = (const float4*)(&s_xn[row][0]);
        float acc=0.f;
        #pragma unroll
        for(int k4=0;k4<8;k4++){
          float4 xv = xr4[k4];
          acc += xv.x*wreg_in[k4*4+0] + xv.y*wreg_in[k4*4+1]
               + xv.z*wreg_in[k4*4+2] + xv.w*wreg_in[k4*4+3];
        }
        if(chunk==0 && row<4) acc = 0.f;
        s_xzf[row-1][e] = acc;
      }
    } else {
      int r0 = 4 + hh*16, r1 = r0 + 16;
      for(int row=r0; row<r1; ++row){
        const float4* xr4 = (const float4*)(&s_xn[row][0]);
        float acc=0.f;
        #pragma unroll
        for(int k4=0;k4<8;k4++){
          float4 xv = xr4[k4];
          acc += xv.x*wreg_in[k4*4+0] + xv.y*wreg_in[k4*4+1]
               + xv.z*wreg_in[k4*4+2] + xv.w*wreg_in[k4*4+3];
        }
        zb[((size_t)seq*LSEQ + l0+row-4)*64 + (e-64)] = acc;
      }
    }
  }
  // x_proj B/C weight row in registers (issued here; used after next syncs)
  const int o2 = t&31, rg = t>>5;
  float wreg[64];
  {
    const float4* wp = (const float4*)(xp_w + (size_t)m*2176 + (size_t)(2+o2)*64);
    #pragma unroll
    for(int k4=0;k4<16;k4++){
      float4 v = wp[k4];
      wreg[k4*4+0]=v.x; wreg[k4*4+1]=v.y; wreg[k4*4+2]=v.z; wreg[k4*4+3]=v.w;
    }
  }
  __syncthreads();

  // ---- conv + silu (xi in regs; input from s_xzf) ----
  float xir[8];
  {
    float lz[11];
    #pragma unroll
    for(int i=0;i<11;i++) lz[i] = s_xzf[r*8+i][d];
    float cw0=s_cwT[0][d], cw1=s_cwT[1][d], cw2=s_cwT[2][d], cw3=s_cwT[3][d], cb=s_cb[d];
    #pragma unroll
    for(int i=0;i<8;i++){
      float xc = cb + lz[i]*cw0 + lz[i+1]*cw1 + lz[i+2]*cw2 + lz[i+3]*cw3;
      xir[i] = silu_f(xc);
      s_xi[(r*8+i)*64 + d] = xir[i];
    }
  }

  // ---- dt_low dots via parity-split shfl butterfly (from regs) ----
  {
    float pr[8];
    #pragma unroll
    for(int i=0;i<8;i++){
      float p0 = xir[i]*s_xpw01[0][d];
      float p1 = xir[i]*s_xpw01[1][d];
      float q0 = p0 + __shfl_xor(p0,1);
      float q1 = p1 + __shfl_xor(p1,1);
      pr[i] = (d&1) ? q1 : q0;
    }
    #pragma unroll
    for(int off=2; off<64; off<<=1){
      #pragma unroll
      for(int i=0;i<8;i++) pr[i] += __shfl_xor(pr[i], off);
    }
    if(d<2){
      #pragma unroll
      for(int i=0;i<8;i++) s_dbc[r*8+i][d] = pr[i];
    }
  }
  __syncthreads();

  // ---- dt proj + softplus; write s_dl + dxb (dl,xi) ----
  {
    float w0=s_dtw[d*2], w1=s_dtw[d*2+1], bb=s_dtb[d];
    #pragma unroll
    for(int i=0;i<8;i++){
      int ll=r*8+i;
      float dtv = s_dbc[ll][0]*w0 + s_dbc[ll][1]*w1 + bb;
      float dlv = softplus_f(dtv);
      s_dl[ll*64 + d] = dlv;
      *(float2*)(dxb + ((size_t)seq*LSEQ + l0+ll)*128 + d*2) = make_float2(dlv, xir[i]);
    }
  }

  // ---- x_proj B/C: all 256 threads, output 2+o2, 4 rows each ----
  {
    #pragma unroll
    for(int ip=0; ip<2; ip++){
      int ll = rg*4 + ip*2;
      const float4* xa=(const float4*)(s_xi + ll*64);
      const float4* xb=(const float4*)(s_xi + (ll+1)*64);
      float a0=0.f,a1=0.f,b0=0.f,b1=0.f;
      #pragma unroll
      for(int k=0;k<16;k+=2){
        float4 u=xa[k], u2=xa[k+1], v=xb[k], v2=xb[k+1];
        a0 += u.x *wreg[4*k+0]+u.y *wreg[4*k+1]+u.z *wreg[4*k+2]+u.w *wreg[4*k+3];
        a1 += u2.x*wreg[4*k+4]+u2.y*wreg[4*k+5]+u2.z*wreg[4*k+6]+u2.w*wreg[4*k+7];
        b0 += v.x *wreg[4*k+0]+v.y *wreg[4*k+1]+v.z *wreg[4*k+2]+v.w *wreg[4*k+3];
        b1 += v2.x*wreg[4*k+4]+v2.y*wreg[4*k+5]+v2.z*wreg[4*k+6]+v2.w*wreg[4*k+7];
      }
      float A=a0+a1, Bv=b0+b1;
      if(o2<16){
        s_bS[ll][o2]=A; s_bS[ll+1][o2]=Bv;
        bmb[((size_t)seq*LSEQ + l0+ll  )*16 + o2]=A;
        bmb[((size_t)seq*LSEQ + l0+ll+1)*16 + o2]=Bv;
      } else {
        cmb[((size_t)seq*LSEQ + l0+ll  )*16 + o2-16]=A;
        cmb[((size_t)seq*LSEQ + l0+ll+1)*16 + o2-16]=Bv;
      }
    }
  }
  __syncthreads();

  // ---- fused chunk summary: thread = (d, s-quad sq=r), 4 states each ----
  {
    const int sq = r;              // wave-uniform
    float as_q[4], as0;
    {
      const float* ap = A_log + (size_t)m*1024 + d*16;
      as0 = -expf(ap[0])*LOG2E;
      #pragma unroll
      for(int k=0;k<4;k++) as_q[k] = -expf(ap[sq*4+k])*LOG2E;
    }
    bool stl = true;
    #pragma unroll
    for(int k=0;k<4;k++){ float ex=(float)(sq*4+k+1)*as0; stl = stl && (fabsf(as_q[k]-ex) <= 1e-4f*fabsf(ex)); }
    const bool structured = (__ballot(stl) == ~0ull);

    float E[4] = {0.f,0.f,0.f,0.f};
    float Sdl = 0.f;

    #define PSTEPF(i_, P0CODE) { \
      float dl = s_dl[(i_)*64 + d]; \
      float u  = dl * s_xi[(i_)*64 + d]; \
      Sdl += dl; \
      const float4 bv = *(const float4*)(&s_bS[i_][sq*4]); \
      float qv = fexp2(dl*as0); \
      float q2 = qv*qv; float q4 = q2*q2; (void)q2; (void)q4; \
      float p0 = (P0CODE); \
      float p1 = p0*qv, p2 = p1*qv, p3 = p2*qv; \
      E[0]=fmaf(p0,E[0],u*bv.x); E[1]=fmaf(p1,E[1],u*bv.y); \
      E[2]=fmaf(p2,E[2],u*bv.z); E[3]=fmaf(p3,E[3],u*bv.w); }

    #define PSTEPG(i_) { \
      float dl = s_dl[(i_)*64 + d]; \
      float u  = dl * s_xi[(i_)*64 + d]; \
      Sdl += dl; \
      const float4 bv = *(const float4*)(&s_bS[i_][sq*4]); \
      float p_[4]; \
      _Pragma("unroll") for(int k=0;k<4;k++) p_[k]=fexp2(dl*as_q[k]); \
      E[0]=fmaf(p_[0],E[0],u*bv.x); E[1]=fmaf(p_[1],E[1],u*bv.y); \
      E[2]=fmaf(p_[2],E[2],u*bv.z); E[3]=fmaf(p_[3],E[3],u*bv.w); }

    if(structured){
      if(sq==0){
        #pragma unroll 4
        for(int i=0;i<LC;i++){ PSTEPF(i, qv) }
      } else if(sq==1){
        #pragma unroll 4
        for(int i=0;i<LC;i++){ PSTEPF(i, q4*qv) }
      } else if(sq==2){
        #pragma unroll 4
        for(int i=0;i<LC;i++){ PSTEPF(i, (q4*q4)*qv) }
      } else {
        #pragma unroll 4
        for(int i=0;i<LC;i++){ PSTEPF(i, ((q4*q4)*q4)*qv) }
      }
    } else {
      #pragma unroll 4
      for(int i=0;i<LC;i++){ PSTEPG(i) }
    }
    #undef PSTEPF
    #undef PSTEPG

    size_t oo=(((size_t)seq*NC+chunk)*64+d)*16 + sq*4;
    *(float4*)(pb+oo) = make_float4(fexp2(Sdl*as_q[0]),fexp2(Sdl*as_q[1]),
                                    fexp2(Sdl*as_q[2]),fexp2(Sdl*as_q[3]));
    *(float4*)(eb+oo) = make_float4(E[0],E[1],E[2],E[3]);
  }
}

// ---------------- K3b: combine chunk summaries, batched prefetch; hs written in-place into p ----------------
__global__ __launch_bounds__(256) void k3b_combine(
  float* p_hs, const float* __restrict__ eb)
{
  const int seq=blockIdx.y, q=blockIdx.x, t=threadIdx.x;
  const size_t elem = (size_t)q*256+t;
  #define OFF(c_) (((size_t)seq*NC+(c_))*1024 + elem)
  float pA[16],eA[16],pB[16],eB[16];
  #pragma unroll
  for(int k=0;k<16;k++){ pA[k]=p_hs[OFF(k)]; eA[k]=eb[OFF(k)]; }
  float h=0.f;
  for(int bt=0; bt<8; bt+=2){
    if(bt+1<8){
      #pragma unroll
      for(int k=0;k<16;k++){ pB[k]=p_hs[OFF((bt+1)*16+k)]; eB[k]=eb[OFF((bt+1)*16+k)]; }
    }
    #pragma unroll
    for(int k=0;k<16;k++){ p_hs[OFF(bt*16+k)]=h; h=fmaf(pA[k],h,eA[k]); }
    if(bt+2<8){
      #pragma unroll
      for(int k=0;k<16;k++){ pA[k]=p_hs[OFF((bt+2)*16+k)]; eA[k]=eb[OFF((bt+2)*16+k)]; }
    }
    #pragma unroll
    for(int k=0;k<16;k++){ p_hs[OFF((bt+1)*16+k)]=h; h=fmaf(pB[k],h,eB[k]); }
  }
  #undef OFF
}

// -------- K3C4: rescan + gate + out_proj + skip. 2 chunks x 2 s-half waves, y planes in LDS --------
__global__ __launch_bounds__(256) void k3c4_scan_outproj(
  const int* __restrict__ did, const float* __restrict__ A_log, const float* __restrict__ Dp,
  const float* __restrict__ dxb,
  const float* __restrict__ bmb, const float* __restrict__ cmb,
  const float* __restrict__ zb, const float* __restrict__ hsb,
  const float* __restrict__ out_w, const float* __restrict__ skipv,
  const float* __restrict__ xnb, float* __restrict__ xmb)
{
  const int seq=blockIdx.y, j=seq>>2, p=seq&3, t=threadIdx.x;
  const int wave=t>>6, d=t&63;
  const int cl=wave>>1, sh=wave&1, sh8=sh*8;
  const int chunk=blockIdx.x*2+cl;
  const int l0=blockIdx.x*2*LC;            // 64 l per block
  const int m=mixer_of(did,j);
  __shared__ float s_b[2*LC*NS];           // 4KB
  __shared__ float s_c[2*LC*NS];           // 4KB
  __shared__ float s_y0[64*64];            // 16KB
  __shared__ float s_y1[64*64];            // 16KB
  {
    const float4* bsrc=(const float4*)(bmb + ((size_t)seq*LSEQ + l0)*NS);
    const float4* csrc=(const float4*)(cmb + ((size_t)seq*LSEQ + l0)*NS);
    ((float4*)s_b)[t]=bsrc[t];
    ((float4*)s_c)[t]=csrc[t];
  }
  float as_h[8], as0;
  {
    const float* ap = A_log + (size_t)m*1024 + d*16;
    as0 = -expf(ap[0])*LOG2E;
    #pragma unroll
    for(int k=0;k<8;k++) as_h[k] = -expf(ap[sh8+k])*LOG2E;
  }
  bool stl = true;
  #pragma unroll
  for(int k=0;k<8;k++){ float ex=(float)(sh8+k+1)*as0; stl = stl && (fabsf(as_h[k]-ex) <= 1e-4f*fabsf(ex)); }
  const bool structured = (__ballot(stl) == ~0ull);

  const float dpv2 = (sh==0) ? Dp[m*64+d] : 0.f;
  float h[8];
  {
    const float4* hp=(const float4*)(hsb + (((size_t)seq*NC+chunk)*64+d)*16 + sh8);
    float4 v0=hp[0], v1=hp[1];
    h[0]=v0.x; h[1]=v0.y; h[2]=v0.z; h[3]=v0.w;
    h[4]=v1.x; h[5]=v1.y; h[6]=v1.z; h[7]=v1.w;
  }
  const float2* dxp=(const float2*)(dxb + ((size_t)seq*LSEQ + (size_t)chunk*LC)*128);
  float* s_yw = sh ? s_y1 : s_y0;
  __syncthreads();

  // FAST: pz[k] = q^(8sh+1+k), ONE exp2 per step
  #define CSTEPF(i_, dx_, P0CODE) { \
    float dl=dx_.x, xv=dx_.y; float u=dl*xv; \
    const float4* bq=(const float4*)(s_b + cl*(LC*NS) + (i_)*NS + sh8); \
    const float4* cq=(const float4*)(s_c + cl*(LC*NS) + (i_)*NS + sh8); \
    float4 b0=bq[0],b1=bq[1],c0=cq[0],c1=cq[1]; \
    float bb[8]={b0.x,b0.y,b0.z,b0.w, b1.x,b1.y,b1.z,b1.w}; \
    float cc2[8]={c0.x,c0.y,c0.z,c0.w, c1.x,c1.y,c1.z,c1.w}; \
    float qv=fexp2(dl*as0); \
    float q2=qv*qv; float q4=q2*q2; (void)q2; (void)q4; \
    float pz[8]; pz[0]=(P0CODE); \
    _Pragma("unroll") for(int k=1;k<8;k++) pz[k]=pz[k-1]*qv; \
    float ya=0.f, yb2=0.f; \
    _Pragma("unroll") for(int k=0;k<8;k++){ \
      h[k]=fmaf(pz[k],h[k],u*bb[k]); \
      float hv=h[k]*cc2[k]; \
      if(k&1) yb2+=hv; else ya+=hv; } \
    float y=ya+yb2; y=fmaf(dpv2,xv,y); \
    s_yw[(cl*LC+(i_))*64 + d]=y; }

  #define CSTEPG(i_, dx_) { \
    float dl=dx_.x, xv=dx_.y; float u=dl*xv; \
    const float4* bq=(const float4*)(s_b + cl*(LC*NS) + (i_)*NS + sh8); \
    const float4* cq=(const float4*)(s_c + cl*(LC*NS) + (i_)*NS + sh8); \
    float4 b0=bq[0],b1=bq[1],c0=cq[0],c1=cq[1]; \
    float bb[8]={b0.x,b0.y,b0.z,b0.w, b1.x,b1.y,b1.z,b1.w}; \
    float cc2[8]={c0.x,c0.y,c0.z,c0.w, c1.x,c1.y,c1.z,c1.w}; \
    float pz[8]; \
    _Pragma("unroll") for(int k=0;k<8;k++) pz[k]=fexp2(dl*as_h[k]); \
    float ya=0.f, yb2=0.f; \
    _Pragma("unroll") for(int k=0;k<8;k++){ \
      h[k]=fmaf(pz[k],h[k],u*bb[k]); \
      float hv=h[k]*cc2[k]; \
      if(k&1) yb2+=hv; else ya+=hv; } \
    float y=ya+yb2; y=fmaf(dpv2,xv,y); \
    s_yw[(cl*LC+(i_))*64 + d]=y; }

  #define CLOOPF(P0CODE) { \
    float2 dxw[4]; \
    _Pragma("unroll") for(int k=0;k<4;k++) dxw[k]=dxp[k*64+d]; \
    for(int ii=0;ii<LC;ii+=4){ \
      float2 c0w=dxw[0],c1w=dxw[1],c2w=dxw[2],c3w=dxw[3]; \
      if(ii+4<LC){ _Pragma("unroll") for(int k=0;k<4;k++) dxw[k]=dxp[(ii+4+k)*64+d]; } \
      CSTEPF(ii+0,c0w,P0CODE); CSTEPF(ii+1,c1w,P0CODE); \
      CSTEPF(ii+2,c2w,P0CODE); CSTEPF(ii+3,c3w,P0CODE); } }

  if(structured){
    if(sh==0){ CLOOPF(qv) }
    else     { CLOOPF((q4*q4)*qv) }
  } else {
    float2 dxw[4];
    #pragma unroll
    for(int k=0;k<4;k++) dxw[k]=dxp[k*64+d];
    for(int ii=0;ii<LC;ii+=4){
      float2 c0w=dxw[0],c1w=dxw[1],c2w=dxw[2],c3w=dxw[3];
      if(ii+4<LC){
        #pragma unroll
        for(int k=0;k<4;k++) dxw[k]=dxp[(ii+4+k)*64+d];
      }
      CSTEPG(ii+0,c0w); CSTEPG(ii+1,c1w); CSTEPG(ii+2,c2w); CSTEPG(ii+3,c3w);
    }
  }
  #undef CLOOPF
  #undef CSTEPF
  #undef CSTEPG

  __syncthreads();
  // gate pass: yg = (y0+y1)*silu(z), into s_y0
  {
    const float* zp = zb + ((size_t)seq*LSEQ + l0)*64;
    #pragma unroll
    for(int it=0; it<16; ++it){
      int idx = t + it*256;
      float ysum = s_y0[idx] + s_y1[idx];
      s_y0[idx] = ysum * silu_f(zp[idx]);
    }
  }
  const int o=t&31, grp=t>>5;
  float wreg[64];
  {
    const float4* wp=(const float4*)(out_w + (size_t)m*2048 + (size_t)o*64);
    #pragma unroll
    for(int k4=0;k4<16;k4++){
      float4 v=wp[k4];
      wreg[k4*4+0]=v.x; wreg[k4*4+1]=v.y; wreg[k4*4+2]=v.z; wreg[k4*4+3]=v.w;
    }
  }
  const float sk=skipv[m];
  __syncthreads();
  for(int ll=grp; ll<64; ll+=8){
    const float4* ya=(const float4*)&s_y0[ll*64];
    float a0=0.f,a1=0.f;
    #pragma unroll
    for(int k=0;k<16;k+=2){
      float4 u=ya[k], u2=ya[k+1];
      a0 += u.x *wreg[4*k+0]+u.y *wreg[4*k+1]+u.z *wreg[4*k+2]+u.w *wreg[4*k+3];
      a1 += u2.x*wreg[4*k+4]+u2.y*wreg[4*k+5]+u2.z*wreg[4*k+6]+u2.w*wreg[4*k+7];
    }
    size_t xidx=((size_t)j*LSEQ + l0+ll)*128 + p*32 + o;
    xmb[xidx]=(a0+a1) + sk*xnb[xidx];
  }
}

// ---------------- K5: LN2 + proj, both experts, 8 l per block ----------------
__global__ __launch_bounds__(256) void k5_ln2_proj(
  const int* __restrict__ did, const float* __restrict__ ln_g, const float* __restrict__ ln_b,
  const float* __restrict__ proj_w, const float* __restrict__ proj_b,
  const float* __restrict__ xmb, float* __restrict__ out)
{
  const int b=blockIdx.y, l0=blockIdx.x*8, t=threadIdx.x;
  const int eh = t>>7, local = t&127;
  const int j = 2*b+eh;
  const int m = mixer_of(did, j);
  __shared__ float s_xn[2][8][132];
  __shared__ float s_comb[8][132];
  __shared__ float s_murs[2][8][2];

  for(int idx=local; idx<1024; idx+=128){
    int ll=idx>>7, c=idx&127;
    s_xn[eh][ll][c] = xmb[((size_t)j*LSEQ + l0+ll)*128 + c];
  }
  __syncthreads();
  if(((t>>6)&1)==0){
    const int lane = t&63;
    const int g = lane&7, ll = lane>>3;
    float sum=0.f, vs=0.f;
    const float4* xr4 = (const float4*)(&s_xn[eh][ll][g*16]);
    #pragma unroll
    for(int k=0;k<4;k++){
      float4 v = xr4[k];
      sum += (v.x+v.y)+(v.z+v.w);
      vs  += v.x*v.x + v.y*v.y + v.z*v.z + v.w*v.w;
    }
    sum += __shfl_xor(sum,1); vs += __shfl_xor(vs,1);
    sum += __shfl_xor(sum,2); vs += __shfl_xor(vs,2);
    sum += __shfl_xor(sum,4); vs += __shfl_xor(vs,4);
    float mu  = sum*(1.f/128.f);
    float var = fmaxf(vs*(1.f/128.f) - mu*mu, 0.f);
    if(g==0){ s_murs[eh][ll][0]=mu; s_murs[eh][ll][1]=rsqrtf(var+1e-5f); }
  }
  __syncthreads();
  for(int idx=local; idx<1024; idx+=128){
    int ll=idx>>7, c=idx&127;
    float xn=(s_xn[eh][ll][c]-s_murs[eh][ll][0])*s_murs[eh][ll][1]*ln_g[m*128+c]+ln_b[m*128+c];
    s_xn[eh][ll][c]=xn;
  }
  __syncthreads();
  float acc[8];
  #pragma unroll
  for(int ll=0;ll<8;ll++) acc[ll]=0.f;
  {
    const float4* pw4 = (const float4*)(proj_w + (size_t)m*16384 + (size_t)local*128);
    #pragma unroll 4
    for(int c4=0;c4<32;c4++){
      float4 w = pw4[c4];
      int c = c4*4;
      #pragma unroll
      for(int ll=0;ll<8;ll++){
        acc[ll] += w.x*s_xn[eh][ll][c] + w.y*s_xn[eh][ll][c+1]
                 + w.z*s_xn[eh][ll][c+2] + w.w*s_xn[eh][ll][c+3];
      }
    }
  }
  float pb_v = proj_b[m*128+local];
  if(eh==0){
    #pragma unroll
    for(int ll=0;ll<8;ll++) s_comb[ll][local]=acc[ll]+pb_v;
  }
  __syncthreads();
  if(eh==1){
    #pragma unroll
    for(int ll=0;ll<8;ll++) s_comb[ll][local]+=acc[ll]+pb_v;
  }
  __syncthreads();
  for(int idx=t; idx<1024; idx+=256){
    int o=idx>>3, ll=idx&7;
    out[((size_t)b*128+o)*LSEQ + l0+ll] = s_comb[ll][o];
  }
}

extern "C" void kernel_launch(void* const* d_in, const int* in_sizes, int n_in,
                              void* d_out, int out_size, void* d_ws, size_t ws_size,
                              hipStream_t stream) {
  const float* x      = (const float*)d_in[0];
  const int*   did    = (const int*)d_in[1];
  const float* ln_g   = (const float*)d_in[2];
  const float* ln_b   = (const float*)d_in[3];
  const float* in_w   = (const float*)d_in[4];
  const float* conv_w = (const float*)d_in[5];
  const float* conv_b = (const float*)d_in[6];
  const float* xp_w   = (const float*)d_in[7];
  const float* dt_w   = (const float*)d_in[8];
  const float* dt_b   = (const float*)d_in[9];
  const float* A_log  = (const float*)d_in[10];
  const float* Dp     = (const float*)d_in[11];
  const float* out_w  = (const float*)d_in[12];
  const float* proj_w = (const float*)d_in[13];
  const float* proj_b = (const float*)d_in[14];
  const float* skipv  = (const float*)d_in[15];
  float* out = (float*)d_out;
  float* ws  = (float*)d_ws;

  float* xnb = ws;                                   // NJ*L*128   (2.10M f)
  float* zb  = xnb + (size_t)NJ*LSEQ*128;            // NSEQ*L*64
  float* dxb = zb  + (size_t)NSEQ*LSEQ*64;           // NSEQ*L*64*2 packed (dl,xi)
  float* bmb = dxb + (size_t)NSEQ*LSEQ*128;          // NSEQ*L*16
  float* cmb = bmb + (size_t)NSEQ*LSEQ*16;           // NSEQ*L*16
  float* xmb = cmb + (size_t)NSEQ*LSEQ*16;           // NJ*L*128
  float* pb  = xmb + (size_t)NJ*LSEQ*128;            // NSEQ*NC*1024 = 2.10M; hs in-place via k3b
  float* eb  = pb  + (size_t)NSEQ*NC*1024;           // 2.10M
  float* hsb = pb;

  hipLaunchKernelGGL(k12_fused, dim3(NC,NSEQ), dim3(256), 0, stream,
                     x,did,ln_g,ln_b,in_w,conv_w,conv_b,xp_w,dt_w,dt_b,A_log,
                     xnb,zb,dxb,bmb,cmb,pb,eb);
  hipLaunchKernelGGL(k3b_combine, dim3(4,NSEQ), dim3(256), 0, stream, pb,eb);
  hipLaunchKernelGGL(k3c4_scan_outproj, dim3(NC/2,NSEQ), dim3(256), 0, stream,
                     did,A_log,Dp,dxb,bmb,cmb,zb,hsb,out_w,skipv,xnb,xmb);
  hipLaunchKernelGGL(k5_ln2_proj, dim3(LSEQ/8,2), dim3(256), 0, stream,
                     did,ln_g,ln_b,proj_w,proj_b,xmb,out);
}